// Round 6
// baseline (123.836 us; speedup 1.0000x reference)
//
#include <hip/hip_runtime.h>

#define NN 128
#define CC_ 16
#define HH 32
#define WW 32
#define DD 4096   // 16*16*16 pooled features per sample
#define ND (NN*DD)

typedef float v2f __attribute__((ext_vector_type(2)));

// c = sqrt(0.5*log2(e)); folded into the means so the per-term exponent is
// exp2(-(q*q)) with the negate absorbed by the v_exp input modifier.
#define MU_SCALE 0.8493218002880191f

// ---------------------------------------------------------------------------
// Kernel 1: fused 2x2 avg-pool, INTERLEAVED output layout for packed math:
//   wm[n*DD+d] = {MU_SCALE*ma, MU_SCALE*mb}   (float2)
//   wv[n*DD+d] = {va, vb}                     (float2), v = avgpool(exp(lv))/4
// Thread 0 zeroes d_out (poisoned 0xAA before every launch).
// ---------------------------------------------------------------------------
__global__ __launch_bounds__(256) void pool_kernel(
    const float* __restrict__ mu_a, const float* __restrict__ lv_a,
    const float* __restrict__ mu_b, const float* __restrict__ lv_b,
    float2* __restrict__ wm, float2* __restrict__ wv, float* __restrict__ out)
{
    int t = blockIdx.x * 256 + threadIdx.x;
    if (t == 0) out[0] = 0.0f;

    int wo = t & 15;
    int ho = (t >> 4) & 15;
    int c  = (t >> 8) & 15;
    int n  = t >> 12;

    int base = ((n * CC_ + c) * HH + 2 * ho) * WW + 2 * wo;  // even -> 8B aligned

    float2 a0 = *(const float2*)(mu_a + base);
    float2 a1 = *(const float2*)(mu_a + base + WW);
    float2 la0 = *(const float2*)(lv_a + base);
    float2 la1 = *(const float2*)(lv_a + base + WW);
    float2 b0 = *(const float2*)(mu_b + base);
    float2 b1 = *(const float2*)(mu_b + base + WW);
    float2 lb0 = *(const float2*)(lv_b + base);
    float2 lb1 = *(const float2*)(lv_b + base + WW);

    const float ms = 0.25f * MU_SCALE;
    float ma_v = ms * (a0.x + a0.y + a1.x + a1.y);
    float mb_v = ms * (b0.x + b0.y + b1.x + b1.y);
    float va_v = 0.0625f * (__expf(la0.x) + __expf(la0.y) + __expf(la1.x) + __expf(la1.y));
    float vb_v = 0.0625f * (__expf(lb0.x) + __expf(lb0.y) + __expf(lb1.x) + __expf(lb1.y));

    wm[t] = make_float2(ma_v, mb_v);
    wv[t] = make_float2(va_v, vb_v);
}

// ---------------------------------------------------------------------------
// Kernel 2: fused pair sums, packed-f32 math + TRIANGLE SYMMETRY.
//   vaa/vbb are (i,j)-symmetric: compute only j<i at weight 2 (+diag at 1),
//   fold as HALF-weights {1, 0.5, 0} so a single final x2 recovers
//   2*(aa + bb - ab). Cuts transcendental work to 2/3.
// Per block: i-tile of 4 rows, j-chunk of 32; j-loop split into three
// wave-uniform ranges: below-diag (aa+bb+ab), 4-wide band (weighted), above
// (ab only). Grid: x = 16 d-chunks; y = 128 = (i-tile, j-chunk).
// ---------------------------------------------------------------------------
#define JCHUNK 32

__device__ __forceinline__ void pair_group(
    v2f& acc, v2f mi, v2f mj, v2f vi, v2f vj)
{
    v2f dd = mi - mj;          // v_pk_add (neg)
    v2f s  = vi + vj;          // v_pk_add
    v2f r;
    r.x = __builtin_amdgcn_rsqf(s.x);
    r.y = __builtin_amdgcn_rsqf(s.y);
    v2f q  = dd * r;           // v_pk_mul
    v2f qq = q * q;            // v_pk_mul
    v2f e;
    e.x = __builtin_amdgcn_exp2f(-qq.x);
    e.y = __builtin_amdgcn_exp2f(-qq.y);
    acc += e * r;              // v_pk_fma
}

__device__ __forceinline__ void pair_group_w(
    v2f& acc, v2f w, v2f mi, v2f mj, v2f vi, v2f vj)
{
    v2f dd = mi - mj;
    v2f s  = vi + vj;
    v2f r;
    r.x = __builtin_amdgcn_rsqf(s.x);
    r.y = __builtin_amdgcn_rsqf(s.y);
    v2f q  = dd * r;
    v2f qq = q * q;
    v2f e;
    e.x = __builtin_amdgcn_exp2f(-qq.x);
    e.y = __builtin_amdgcn_exp2f(-qq.y);
    v2f er = e * r;            // v_pk_mul
    acc += w * er;             // v_pk_fma
}

__global__ __launch_bounds__(256) void pair_kernel(
    const float2* __restrict__ wm, const float2* __restrict__ wv,
    float* __restrict__ out)
{
    const int d  = blockIdx.x * 256 + threadIdx.x;
    const int i0 = (blockIdx.y >> 2) * 4;
    const int j0 = (blockIdx.y & 3) * JCHUNK;
    const int hi = j0 + JCHUNK;

    // Load 4 i-rows, repack by tensor: pma[p] = {ma[i0+2p], ma[i0+2p+1]} etc.
    v2f pma[2], pmb[2], pva[2], pvb[2];
#pragma unroll
    for (int p = 0; p < 2; ++p) {
        float2 m0 = wm[(i0 + 2 * p) * DD + d];
        float2 m1 = wm[(i0 + 2 * p + 1) * DD + d];
        float2 v0 = wv[(i0 + 2 * p) * DD + d];
        float2 v1 = wv[(i0 + 2 * p + 1) * DD + d];
        pma[p] = (v2f){m0.x, m1.x};
        pmb[p] = (v2f){m0.y, m1.y};
        pva[p] = (v2f){v0.x, v1.x};
        pvb[p] = (v2f){v0.y, v1.y};
    }

    v2f acc_aa = (v2f){0.0f, 0.0f};
    v2f acc_bb = (v2f){0.0f, 0.0f};
    v2f acc_ab = (v2f){0.0f, 0.0f};

    const int below_end = min(hi, i0);        // j in [j0, below_end): j < all i rows
    const int band_lo   = max(j0, i0);        // j in [band_lo, band_hi): diagonal band
    const int band_hi   = min(hi, i0 + 4);
    const int above_lo  = max(j0, i0 + 4);    // j in [above_lo, hi): j > all i rows

    // --- below diagonal: full aa + bb + ab (half-weight 1 implied) ---
#pragma unroll 2
    for (int j = j0; j < below_end; ++j) {
        float2 jm = wm[j * DD + d];
        float2 jv = wv[j * DD + d];
        v2f jma2 = (v2f){jm.x, jm.x};
        v2f jmb2 = (v2f){jm.y, jm.y};
        v2f jva2 = (v2f){jv.x, jv.x};
        v2f jvb2 = (v2f){jv.y, jv.y};
#pragma unroll
        for (int p = 0; p < 2; ++p) {
            pair_group(acc_aa, pma[p], jma2, pva[p], jva2);
            pair_group(acc_bb, pmb[p], jmb2, pvb[p], jvb2);
            pair_group(acc_ab, pma[p], jmb2, pva[p], jvb2);
        }
    }

    // --- diagonal band (<=4 iters): per-row half-weights {1, .5, 0} ---
    for (int j = band_lo; j < band_hi; ++j) {
        float2 jm = wm[j * DD + d];
        float2 jv = wv[j * DD + d];
        v2f jma2 = (v2f){jm.x, jm.x};
        v2f jmb2 = (v2f){jm.y, jm.y};
        v2f jva2 = (v2f){jv.x, jv.x};
        v2f jvb2 = (v2f){jv.y, jv.y};
        v2f w[2];
#pragma unroll
        for (int p = 0; p < 2; ++p) {
            int r0 = i0 + 2 * p, r1 = r0 + 1;
            w[p].x = (j < r0) ? 1.0f : (j == r0 ? 0.5f : 0.0f);
            w[p].y = (j < r1) ? 1.0f : (j == r1 ? 0.5f : 0.0f);
        }
#pragma unroll
        for (int p = 0; p < 2; ++p) {
            pair_group_w(acc_aa, w[p], pma[p], jma2, pva[p], jva2);
            pair_group_w(acc_bb, w[p], pmb[p], jmb2, pvb[p], jvb2);
            pair_group(acc_ab, pma[p], jmb2, pva[p], jvb2);
        }
    }

    // --- above diagonal: ab only ---
#pragma unroll 2
    for (int j = above_lo; j < hi; ++j) {
        float2 jm = wm[j * DD + d];
        float2 jv = wv[j * DD + d];
        v2f jmb2 = (v2f){jm.y, jm.y};
        v2f jvb2 = (v2f){jv.y, jv.y};
#pragma unroll
        for (int p = 0; p < 2; ++p) {
            pair_group(acc_ab, pma[p], jmb2, pva[p], jvb2);
        }
    }

    // vaa + vbb - 2 vab = 2 * (half_aa + half_bb - half_ab)
    float part = 2.0f * ((acc_aa.x + acc_aa.y) + (acc_bb.x + acc_bb.y)
                       - (acc_ab.x + acc_ab.y));

    // wave (64-lane) shuffle reduction
#pragma unroll
    for (int off = 32; off > 0; off >>= 1)
        part += __shfl_down(part, off, 64);

    __shared__ float wsum[4];
    int lane = threadIdx.x & 63;
    int wv_  = threadIdx.x >> 6;
    if (lane == 0) wsum[wv_] = part;
    __syncthreads();
    if (threadIdx.x == 0) {
        float s = wsum[0] + wsum[1] + wsum[2] + wsum[3];
        atomicAdd(out, s);
    }
}

extern "C" void kernel_launch(void* const* d_in, const int* in_sizes, int n_in,
                              void* d_out, int out_size, void* d_ws, size_t ws_size,
                              hipStream_t stream) {
    const float* mu_a = (const float*)d_in[0];
    const float* lv_a = (const float*)d_in[1];
    const float* mu_b = (const float*)d_in[2];
    const float* lv_b = (const float*)d_in[3];
    float* out = (float*)d_out;
    float2* wm = (float2*)d_ws;            // ND float2 = 4 MB
    float2* wv = ((float2*)d_ws) + ND;     // ND float2 = 4 MB

    pool_kernel<<<dim3(ND / 256), 256, 0, stream>>>(mu_a, lv_a, mu_b, lv_b, wm, wv, out);
    pair_kernel<<<dim3(DD / 256, (NN / 4) * (NN / JCHUNK)), 256, 0, stream>>>(wm, wv, out);
}